// Round 1
// baseline (417.011 us; speedup 1.0000x reference)
//
#include <hip/hip_runtime.h>

// Problem constants
#define DIMK 512           // feature dim == block_len
#define NBLK 64            // BATCH*BLOCK_NUM
#define NTOK 32768         // NBLK*512 tokens

typedef short  short8 __attribute__((ext_vector_type(8)));   // 8 bf16 (bit pattern)
typedef float  f32x4  __attribute__((ext_vector_type(4)));
typedef unsigned short u16x8 __attribute__((ext_vector_type(8)));

__device__ __forceinline__ unsigned short f2bf(float f) {
  union { float f; unsigned u; } v; v.f = f;
  unsigned r = (v.u + 0x7FFFu + ((v.u >> 16) & 1u)) >> 16;   // RNE
  return (unsigned short)r;
}
__device__ __forceinline__ float bf2f(unsigned short h) {
  return __uint_as_float(((unsigned)h) << 16);
}

// ---------------------------------------------------------------------------
// Shared 128x128 MFMA GEMM tile body.  C[128,128] += A[128,512] * B[512,128],
// A given row-major [row][k] (bf16 bits), B given TRANSPOSED row-major
// Bt[n][k] (bf16 bits). 4 waves in 2x2, each wave 64x64 via 4x4 16x16x32 MFMAs.
// ---------------------------------------------------------------------------
__device__ __forceinline__ void gemm_tile(
    const unsigned short* __restrict__ A, size_t arow0,
    const unsigned short* __restrict__ Bt, size_t brow0,
    f32x4 acc[4][4], unsigned short* As, unsigned short* Bs)
{
  const int tid  = threadIdx.x;
  const int wv   = tid >> 6;
  const int lane = tid & 63;
  const int quad = lane >> 4;
  const int l16  = lane & 15;
  const int rb   = (wv >> 1) * 64;
  const int cb   = (wv & 1) * 64;

  for (int it = 0; it < 16; ++it) {
    const int k0 = it * 32;
    // stage A tile 128x32 and Bt tile 128x32 (16B vector chunks)
    for (int c = tid; c < 512; c += 256) {
      const int row = c >> 2, off = (c & 3) << 3;
      *(u16x8*)&As[row * 32 + off] =
          *(const u16x8*)&A[(arow0 + row) * (size_t)DIMK + k0 + off];
      *(u16x8*)&Bs[row * 32 + off] =
          *(const u16x8*)&Bt[(brow0 + row) * (size_t)DIMK + k0 + off];
    }
    __syncthreads();
    short8 af[4], bfv[4];
#pragma unroll
    for (int i = 0; i < 4; ++i)
      af[i] = *(const short8*)&As[(rb + i * 16 + l16) * 32 + quad * 8];
#pragma unroll
    for (int j = 0; j < 4; ++j)
      bfv[j] = *(const short8*)&Bs[(cb + j * 16 + l16) * 32 + quad * 8];
#pragma unroll
    for (int i = 0; i < 4; ++i)
#pragma unroll
      for (int j = 0; j < 4; ++j)
        acc[i][j] = __builtin_amdgcn_mfma_f32_16x16x32_bf16(
            af[i], bfv[j], acc[i][j], 0, 0, 0);
    __syncthreads();
  }
}

// ---------------------------------------------------------------------------
// K0a: Wt[w][n][k] = bf16(dw_w[k][n])   (transpose + convert, 3x512x512)
// ---------------------------------------------------------------------------
__global__ __launch_bounds__(256) void k_wt_prep(
    const float* __restrict__ dw1, const float* __restrict__ dw2,
    const float* __restrict__ dw3, unsigned short* __restrict__ Wt)
{
  const int idx = blockIdx.x * 256 + threadIdx.x;   // < 3*262144
  const int w = idx >> 18;
  const int r = idx & 262143;
  const int n = r >> 9, k = r & 511;
  const float* dw = (w == 0) ? dw1 : (w == 1) ? dw2 : dw3;
  Wt[(size_t)w * 262144 + (size_t)n * 512 + k] = f2bf(dw[(size_t)k * 512 + n]);
}

// ---------------------------------------------------------------------------
// K0b: X fp32 -> bf16 bits
// ---------------------------------------------------------------------------
__global__ __launch_bounds__(256) void k_xconv(
    const float* __restrict__ X, unsigned short* __restrict__ Xb)
{
  const size_t i = ((size_t)blockIdx.x * 256 + threadIdx.x) * 8;
  const float4 a = *(const float4*)(X + i);
  const float4 b = *(const float4*)(X + i + 4);
  u16x8 o;
  o[0] = f2bf(a.x); o[1] = f2bf(a.y); o[2] = f2bf(a.z); o[3] = f2bf(a.w);
  o[4] = f2bf(b.x); o[5] = f2bf(b.y); o[6] = f2bf(b.z); o[7] = f2bf(b.w);
  *(u16x8*)(Xb + i) = o;
}

// ---------------------------------------------------------------------------
// K1: Q/K/V = Xb @ dw_w + db_w   (grid.x = w*4 + ntile, grid.y = mtile)
// ---------------------------------------------------------------------------
__global__ __launch_bounds__(256) void k_qkv(
    const unsigned short* __restrict__ Xb, const unsigned short* __restrict__ Wt,
    const float* __restrict__ db1, const float* __restrict__ db2,
    const float* __restrict__ db3,
    unsigned short* __restrict__ Qb, unsigned short* __restrict__ Kb,
    unsigned short* __restrict__ Vb)
{
  __shared__ __align__(16) unsigned short As[128 * 32];
  __shared__ __align__(16) unsigned short Bs[128 * 32];
  const int w  = blockIdx.x >> 2;
  const int nt = blockIdx.x & 3;
  const size_t m0 = (size_t)blockIdx.y * 128;
  const int n0 = nt * 128;
  f32x4 acc[4][4];
#pragma unroll
  for (int i = 0; i < 4; ++i)
#pragma unroll
    for (int j = 0; j < 4; ++j) { f32x4 z = {0.f, 0.f, 0.f, 0.f}; acc[i][j] = z; }

  gemm_tile(Xb, m0, Wt + (size_t)w * 262144, (size_t)n0, acc, As, Bs);

  const float* db = (w == 0) ? db1 : (w == 1) ? db2 : db3;
  unsigned short* Ob = (w == 0) ? Qb : (w == 1) ? Kb : Vb;
  const int lane = threadIdx.x & 63, wv = threadIdx.x >> 6;
  const int quad = lane >> 4, l16 = lane & 15;
  const int rb = (wv >> 1) * 64, cb = (wv & 1) * 64;
#pragma unroll
  for (int i = 0; i < 4; ++i)
#pragma unroll
    for (int j = 0; j < 4; ++j)
#pragma unroll
      for (int r = 0; r < 4; ++r) {
        const size_t row = m0 + rb + i * 16 + quad * 4 + r;
        const int col = n0 + cb + j * 16 + l16;
        Ob[row * (size_t)DIMK + col] = f2bf(acc[i][j][r] + db[col]);
      }
}

// ---------------------------------------------------------------------------
// K2: S = (Q Kt)/sqrt(512) + (1-m)*(-1e10), stored bf16
// grid: x = mtile + 4*ntile (16), y = blk (64)
// ---------------------------------------------------------------------------
__global__ __launch_bounds__(256) void k_scores(
    const unsigned short* __restrict__ Qb, const unsigned short* __restrict__ Kb,
    const float* __restrict__ mask, unsigned short* __restrict__ Sb)
{
  __shared__ __align__(16) unsigned short As[128 * 32];
  __shared__ __align__(16) unsigned short Bs[128 * 32];
  const int blk = blockIdx.y;
  const int mt = blockIdx.x & 3, nt = blockIdx.x >> 2;
  const size_t tb = (size_t)blk * 512;
  f32x4 acc[4][4];
#pragma unroll
  for (int i = 0; i < 4; ++i)
#pragma unroll
    for (int j = 0; j < 4; ++j) { f32x4 z = {0.f, 0.f, 0.f, 0.f}; acc[i][j] = z; }

  gemm_tile(Qb, tb + mt * 128, Kb, tb + nt * 128, acc, As, Bs);

  const float scale = 0.04419417382415922f;   // 1/sqrt(512)
  const int lane = threadIdx.x & 63, wv = threadIdx.x >> 6;
  const int quad = lane >> 4, l16 = lane & 15;
  const int rb = (wv >> 1) * 64, cb = (wv & 1) * 64;
#pragma unroll
  for (int i = 0; i < 4; ++i)
#pragma unroll
    for (int j = 0; j < 4; ++j)
#pragma unroll
      for (int r = 0; r < 4; ++r) {
        const int q = mt * 128 + rb + i * 16 + quad * 4 + r;   // local query
        const int key = nt * 128 + cb + j * 16 + l16;
        const size_t tok = tb + q;
        const float m = mask[tok * (size_t)DIMK + key];
        const float s = acc[i][j][r] * scale + (1.0f - m) * (-1e10f);
        Sb[tok * (size_t)DIMK + key] = f2bf(s);
      }
}

// ---------------------------------------------------------------------------
// K2b: row softmax over 512 keys (1 row / wave), bf16 in, bf16 out
// ---------------------------------------------------------------------------
__global__ __launch_bounds__(256) void k_softmax(
    const unsigned short* __restrict__ Sb, unsigned short* __restrict__ Pb)
{
  const int wv = threadIdx.x >> 6, lane = threadIdx.x & 63;
  const size_t row = (size_t)blockIdx.x * 4 + wv;
  const unsigned short* src = Sb + row * DIMK + lane * 8;
  u16x8 u = *(const u16x8*)src;
  float s[8];
#pragma unroll
  for (int j = 0; j < 8; ++j) s[j] = bf2f(u[j]);
  float mx = s[0];
#pragma unroll
  for (int j = 1; j < 8; ++j) mx = fmaxf(mx, s[j]);
  for (int m = 1; m < 64; m <<= 1) mx = fmaxf(mx, __shfl_xor(mx, m, 64));
  float e[8], sum = 0.f;
#pragma unroll
  for (int j = 0; j < 8; ++j) { e[j] = __expf(s[j] - mx); sum += e[j]; }
  for (int m = 1; m < 64; m <<= 1) sum += __shfl_xor(sum, m, 64);
  const float inv = 1.0f / sum;
  u16x8 o;
#pragma unroll
  for (int j = 0; j < 8; ++j) o[j] = f2bf(e[j] * inv);
  *(u16x8*)(Pb + row * DIMK + lane * 8) = o;
}

// ---------------------------------------------------------------------------
// T: in-place per-block transpose of V (512x512 bf16 per block)
// grid: x = ti*16+tj (256, only ti<=tj active), y = blk
// ---------------------------------------------------------------------------
__global__ __launch_bounds__(256) void k_vt(unsigned short* __restrict__ Vb)
{
  const int ti = blockIdx.x >> 4, tj = blockIdx.x & 15;
  if (ti > tj) return;
  unsigned short* V = Vb + (size_t)blockIdx.y * 262144;
  __shared__ unsigned short TA[32][33];
  __shared__ unsigned short TB[32][33];
  const int c = threadIdx.x & 31, r0 = (threadIdx.x >> 5) * 4;
#pragma unroll
  for (int i = 0; i < 4; ++i)
    TA[r0 + i][c] = V[(size_t)(ti * 32 + r0 + i) * 512 + tj * 32 + c];
  if (ti != tj) {
#pragma unroll
    for (int i = 0; i < 4; ++i)
      TB[r0 + i][c] = V[(size_t)(tj * 32 + r0 + i) * 512 + ti * 32 + c];
  }
  __syncthreads();
  if (ti != tj) {
#pragma unroll
    for (int i = 0; i < 4; ++i)
      V[(size_t)(ti * 32 + r0 + i) * 512 + tj * 32 + c] = TB[c][r0 + i];
#pragma unroll
    for (int i = 0; i < 4; ++i)
      V[(size_t)(tj * 32 + r0 + i) * 512 + ti * 32 + c] = TA[c][r0 + i];
  } else {
#pragma unroll
    for (int i = 0; i < 4; ++i)
      V[(size_t)(ti * 32 + r0 + i) * 512 + tj * 32 + c] = TA[c][r0 + i];
  }
}

// ---------------------------------------------------------------------------
// K3: Out = P @ V + X (residual), fp32 out.  Vt is per-block [dim][tok].
// grid: x = mtile + 4*ntile (16), y = blk (64)
// ---------------------------------------------------------------------------
__global__ __launch_bounds__(256) void k_pv(
    const unsigned short* __restrict__ Pb, const unsigned short* __restrict__ Vt,
    const float* __restrict__ X, float* __restrict__ Out)
{
  __shared__ __align__(16) unsigned short As[128 * 32];
  __shared__ __align__(16) unsigned short Bs[128 * 32];
  const int blk = blockIdx.y;
  const int mt = blockIdx.x & 3, nt = blockIdx.x >> 2;
  const size_t tb = (size_t)blk * 512;
  f32x4 acc[4][4];
#pragma unroll
  for (int i = 0; i < 4; ++i)
#pragma unroll
    for (int j = 0; j < 4; ++j) { f32x4 z = {0.f, 0.f, 0.f, 0.f}; acc[i][j] = z; }

  gemm_tile(Pb, tb + mt * 128, Vt + (size_t)blk * 262144, (size_t)(nt * 128),
            acc, As, Bs);

  const int lane = threadIdx.x & 63, wv = threadIdx.x >> 6;
  const int quad = lane >> 4, l16 = lane & 15;
  const int rb = (wv >> 1) * 64, cb = (wv & 1) * 64;
#pragma unroll
  for (int i = 0; i < 4; ++i)
#pragma unroll
    for (int j = 0; j < 4; ++j)
#pragma unroll
      for (int r = 0; r < 4; ++r) {
        const size_t tok = tb + mt * 128 + rb + i * 16 + quad * 4 + r;
        const int col = nt * 128 + cb + j * 16 + l16;
        Out[tok * (size_t)DIMK + col] =
            acc[i][j][r] + X[tok * (size_t)DIMK + col];
      }
}

// ---------------------------------------------------------------------------
// K4: in-place LayerNorm over last dim (512), eps=1e-3, 1 row / wave
// ---------------------------------------------------------------------------
__global__ __launch_bounds__(256) void k_ln(float* __restrict__ Out)
{
  const int wv = threadIdx.x >> 6, lane = threadIdx.x & 63;
  const size_t row = (size_t)blockIdx.x * 4 + wv;
  float* p = Out + row * DIMK + lane * 8;
  const float4 a = *(const float4*)(p);
  const float4 b = *(const float4*)(p + 4);
  float x[8] = {a.x, a.y, a.z, a.w, b.x, b.y, b.z, b.w};
  float sum = 0.f, sq = 0.f;
#pragma unroll
  for (int j = 0; j < 8; ++j) { sum += x[j]; sq += x[j] * x[j]; }
  for (int m = 1; m < 64; m <<= 1) {
    sum += __shfl_xor(sum, m, 64);
    sq  += __shfl_xor(sq, m, 64);
  }
  const float mean = sum * (1.0f / 512.0f);
  const float var  = sq * (1.0f / 512.0f) - mean * mean;
  const float inv  = rsqrtf(var + 1e-3f);
  float4 oa, ob;
  oa.x = (x[0] - mean) * inv; oa.y = (x[1] - mean) * inv;
  oa.z = (x[2] - mean) * inv; oa.w = (x[3] - mean) * inv;
  ob.x = (x[4] - mean) * inv; ob.y = (x[5] - mean) * inv;
  ob.z = (x[6] - mean) * inv; ob.w = (x[7] - mean) * inv;
  *(float4*)(p) = oa;
  *(float4*)(p + 4) = ob;
}

// ---------------------------------------------------------------------------
extern "C" void kernel_launch(void* const* d_in, const int* in_sizes, int n_in,
                              void* d_out, int out_size, void* d_ws, size_t ws_size,
                              hipStream_t stream)
{
  const float* X    = (const float*)d_in[0];
  const float* mask = (const float*)d_in[1];
  const float* dw1  = (const float*)d_in[2];
  const float* dw2  = (const float*)d_in[3];
  const float* dw3  = (const float*)d_in[4];
  const float* db1  = (const float*)d_in[5];
  const float* db2  = (const float*)d_in[6];
  const float* db3  = (const float*)d_in[7];
  float* Out = (float*)d_out;

  char* ws = (char*)d_ws;
  const size_t MB = 1ull << 20;
  // ws layout (130 MB total, with aliasing):
  //   [0,2MB)    Wt  : 3x512x512 bf16 transposed weights
  //   [2,34)     Qb  : Q bf16 [32768][512]; after softmax re-used as P
  //   [34,66)    Kb  : K bf16
  //   [66,98)    Vb  : V bf16, transposed IN PLACE to [dim][tok] per block
  //   [98,130)   Sb  : scores bf16; also used earlier as Xb (bf16 inputs)
  unsigned short* Wt = (unsigned short*)(ws);
  unsigned short* Qb = (unsigned short*)(ws + 2 * MB);
  unsigned short* Kb = (unsigned short*)(ws + 34 * MB);
  unsigned short* Vb = (unsigned short*)(ws + 66 * MB);
  unsigned short* Sb = (unsigned short*)(ws + 98 * MB);
  unsigned short* Xb = Sb;   // alias: Xb dead once K1 completes
  unsigned short* Pb = Qb;   // alias: Qb dead once K2 completes

  k_wt_prep<<<3072, 256, 0, stream>>>(dw1, dw2, dw3, Wt);
  k_xconv  <<<8192, 256, 0, stream>>>(X, Xb);
  k_qkv    <<<dim3(12, 256), 256, 0, stream>>>(Xb, Wt, db1, db2, db3, Qb, Kb, Vb);
  k_scores <<<dim3(16, 64), 256, 0, stream>>>(Qb, Kb, mask, Sb);
  k_softmax<<<8192, 256, 0, stream>>>(Sb, Pb);
  k_vt     <<<dim3(256, 64), 256, 0, stream>>>(Vb);
  k_pv     <<<dim3(16, 64), 256, 0, stream>>>(Pb, Vb, X, Out);
  k_ln     <<<8192, 256, 0, stream>>>(Out);
}